// Round 2
// baseline (385.463 us; speedup 1.0000x reference)
//
#include <hip/hip_runtime.h>

// Holt-Winters (no trend) batched scan.
// B=32768 series, T=2048 steps, SLEN=24, NPREDS=24.
// One thread per series; seasonal state in registers via unroll-24 static
// indexing; explicit A/B register prefetch of 6xfloat4 per 24-step body.

constexpr int T_LEN  = 2048;
constexpr int SLEN_C = 24;
constexpr int NPRED  = 24;

// one scan step, idx must be compile-time constant
#define STEP(valexpr, idx) do {                         \
    const float v_ = (valexpr);                         \
    const float s_ = seas[(idx)];                       \
    smooth = fmaf(a, v_ - s_, oma * smooth);            \
    seas[(idx)] = fmaf(g, v_ - smooth, omg * s_);       \
} while (0)

// process one 24-step body starting at t = 4 + 24*m; BUF holds 6 float4s
#define BODY(BUF) do {                                          \
    _Pragma("unroll")                                           \
    for (int u = 0; u < 24; ++u) {                              \
        const float4 q_ = (BUF)[u >> 2];                        \
        const int c_ = u & 3;                                   \
        const float val_ = (c_ == 0) ? q_.x :                   \
                           (c_ == 1) ? q_.y :                   \
                           (c_ == 2) ? q_.z : q_.w;             \
        STEP(val_, (4 + u) % 24);                               \
    }                                                           \
} while (0)

// load 6 float4 groups for body m (groups 1+6m .. 6+6m)
#define LOADB(BUF, m) do {                                      \
    _Pragma("unroll")                                           \
    for (int i_ = 0; i_ < 6; ++i_)                              \
        (BUF)[i_] = row[1 + (m) * 6 + i_];                      \
} while (0)

__global__ __launch_bounds__(64) void hw_scan_kernel(
    const float* __restrict__ series,
    const int*   __restrict__ shifts,
    const float* __restrict__ alpha_p,
    const float* __restrict__ gamma_p,
    const float* __restrict__ init_season,
    float*       __restrict__ out)
{
    const int b = blockIdx.x * 64 + threadIdx.x;

    // broadcast init_season through LDS (runtime-gather target)
    __shared__ float is_l[SLEN_C];
    if (threadIdx.x < SLEN_C) is_l[threadIdx.x] = init_season[threadIdx.x];
    __syncthreads();

    const float a   = 1.0f / (1.0f + __expf(-alpha_p[0]));
    const float g   = 1.0f / (1.0f + __expf(-gamma_p[0]));
    const float oma = 1.0f - a;
    const float omg = 1.0f - g;

    // seasonals0[k] = init_season[(k - shift) mod 24]
    const int shift = shifts[b];
    float seas[SLEN_C];
#pragma unroll
    for (int k = 0; k < SLEN_C; ++k) {
        int j = k - shift;
        if (j < 0) j += SLEN_C;
        seas[k] = is_l[j];
    }

    const float4* __restrict__ row =
        reinterpret_cast<const float4*>(series + (size_t)b * T_LEN);

    float smooth;
    // group 0: t=0 init + steps t=1..3 (idx 1..3)
    {
        const float4 v0 = row[0];
        smooth = v0.x;
        STEP(v0.y, 1);
        STEP(v0.z, 2);
        STEP(v0.w, 3);
    }

    // bodies m = 0..84 cover t = 4 .. 2043 (idx pattern (4+u)%24, static)
    float4 bufA[6], bufB[6];
    LOADB(bufA, 0);
    for (int m = 0; m < 84; m += 2) {
        LOADB(bufB, m + 1);
        BODY(bufA);
        LOADB(bufA, m + 2);
        BODY(bufB);
    }
    // loop exits with bodies 0..83 done, bufA = body 84
    const float4 tl = row[(T_LEN / 4) - 1];   // t = 2044..2047
    BODY(bufA);

    // tail steps t=2044..2047, idx = 4..7 (2044 % 24 == 4)
    STEP(tl.x, 4);
    STEP(tl.y, 5);
    STEP(tl.z, 6);
    STEP(tl.w, 7);

    // predictions: out[b][j] = smooth + seas[(2048 + j) % 24], 2048%24 == 8
    float4* __restrict__ o4 =
        reinterpret_cast<float4*>(out + (size_t)b * NPRED);
#pragma unroll
    for (int j4 = 0; j4 < NPRED / 4; ++j4) {
        float4 o;
        o.x = smooth + seas[(8 + j4 * 4 + 0) % 24];
        o.y = smooth + seas[(8 + j4 * 4 + 1) % 24];
        o.z = smooth + seas[(8 + j4 * 4 + 2) % 24];
        o.w = smooth + seas[(8 + j4 * 4 + 3) % 24];
        o4[j4] = o;
    }
}

extern "C" void kernel_launch(void* const* d_in, const int* in_sizes, int n_in,
                              void* d_out, int out_size, void* d_ws, size_t ws_size,
                              hipStream_t stream) {
    const float* series      = (const float*)d_in[0];
    const int*   shifts      = (const int*)  d_in[1];
    const float* alpha_p     = (const float*)d_in[2];
    const float* gamma_p     = (const float*)d_in[3];
    const float* init_season = (const float*)d_in[4];
    float*       out         = (float*)d_out;

    const int Bn = in_sizes[1];           // number of series (32768)
    hw_scan_kernel<<<Bn / 64, 64, 0, stream>>>(
        series, shifts, alpha_p, gamma_p, init_season, out);
}

// Round 3
// 376.279 us; speedup vs baseline: 1.0244x; 1.0244x over previous
//
#include <hip/hip_runtime.h>
#include <stdint.h>

// Holt-Winters (no trend) batched scan — coalesced LDS-staged version.
// B=32768 series (rows of 2048 f32), SLEN=24, NPREDS=24.
// 1 wave (64 threads) per block, 64 series per block, grid = 512.
// Tiles of 64 rows x 96 cols staged via global_load_lds (1KB/instr, source
// pre-swizzled so per-lane ds_read_b128 is bank-conflict-floor), triple
// buffered, 2 tiles of prefetch in flight (counted vmcnt, never 0 mid-loop).

constexpr int T_LEN      = 2048;
constexpr int SLEN_C     = 24;
constexpr int NPRED      = 24;
constexpr int TILE_C     = 96;                  // multiple of 24: seas idx static
constexpr int N_TILES    = 21;                  // 21*96 = 2016
constexpr int TILE_BYTES = 64 * TILE_C * 4;     // 24 KB
constexpr int NBUF       = 3;                   // 72 KB LDS -> 2 blocks/CU

typedef __attribute__((address_space(3))) void       lds_void;
typedef const __attribute__((address_space(1))) void glb_void;

// one scan step; idx MUST be compile-time (seas stays in registers).
// smooth chain = single dependent FMA per step.
#define STEPX(vv, idx) do {                                   \
    const float s_ = seas[(idx)];                             \
    const float d_ = (vv) - s_;                               \
    smooth = fmaf(oma, smooth, a * d_);                       \
    seas[(idx)] = fmaf(g, (vv) - smooth, omg * s_);           \
} while (0)

// stage tile nn (cols [96*nn, 96*nn+96)) into buffer bb: 24 x 1KB DMA.
// LDS dest is linear; source col-group is pre-swizzled (rule #21).
#define STAGE(nn, bb) do {                                                   \
    const uint32_t tb_ = (uint32_t)(nn) * (uint32_t)(TILE_C * 4);            \
    _Pragma("unroll")                                                        \
    for (int k_ = 0; k_ < 24; ++k_) {                                        \
        __builtin_amdgcn_global_load_lds(                                    \
            (glb_void*)(sbase + (size_t)(off32[k_] + tb_)),                  \
            (lds_void*)(lbase + (bb) * TILE_BYTES + k_ * 1024),              \
            16, 0, 0);                                                       \
    }                                                                        \
} while (0)

// 24 steps of body q (q compile-time 0..3) from buffer at byte offset bufb.
// Lane i reads its own row i; slot XOR-swizzle spreads the 64 lanes across
// all 8 bank-quads (volume-floor LDS access).
#define BODY24(bufb, q, FIRST) do {                                          \
    float4 gv_[6];                                                           \
    _Pragma("unroll")                                                        \
    for (int j4_ = 0; j4_ < 6; ++j4_) {                                      \
        const int slot_ = (6 * (q) + j4_) ^ (lane & 7);                      \
        gv_[j4_] = *(const float4*)(lbase + (bufb) + 384 * lane + 16 * slot_);\
    }                                                                        \
    _Pragma("unroll")                                                        \
    for (int j_ = 0; j_ < 24; ++j_) {                                        \
        const float4 q_ = gv_[j_ >> 2];                                      \
        const int c_ = j_ & 3;                                               \
        const float v_ = (c_ == 0) ? q_.x : (c_ == 1) ? q_.y :               \
                         (c_ == 2) ? q_.z : q_.w;                            \
        if ((FIRST) && j_ == 0) { smooth = v_; }                             \
        else                    { STEPX(v_, j_); }                           \
    }                                                                        \
} while (0)

__global__ __launch_bounds__(64) void hw_kernel(
    const float* __restrict__ series,
    const int*   __restrict__ shifts,
    const float* __restrict__ alpha_p,
    const float* __restrict__ gamma_p,
    const float* __restrict__ init_season,
    float*       __restrict__ out)
{
    __shared__ __align__(16) float lds_f[NBUF * 64 * TILE_C];   // 72 KB
    __shared__ float is_l[SLEN_C];

    const int lane = threadIdx.x;
    const int s0   = blockIdx.x * 64;
    const int b    = s0 + lane;

    if (lane < SLEN_C) is_l[lane] = init_season[lane];
    __syncthreads();

    const float a   = 1.0f / (1.0f + __expf(-alpha_p[0]));
    const float g   = 1.0f / (1.0f + __expf(-gamma_p[0]));
    const float oma = 1.0f - a;
    const float omg = 1.0f - g;

    // seasonals0[k] = init_season[(k - shift) mod 24]
    const int shift = shifts[b];
    float seas[SLEN_C];
#pragma unroll
    for (int k = 0; k < SLEN_C; ++k) {
        int j = k - shift;
        if (j < 0) j += SLEN_C;
        seas[k] = is_l[j];
    }

    // Per-lane source byte offsets for the 24 staging instructions of a tile.
    // Instr k covers tile float-offsets [256k, 256k+256): lane L holds
    // x = 64k + L -> row r = x/24, in-row group c4 = x%24; source group is
    // swizzled: gsw = c4 ^ (r&7). Tile-independent; per tile add n*384 bytes.
    uint32_t off32[24];
#pragma unroll
    for (int k = 0; k < 24; ++k) {
        const uint32_t x   = 64u * (uint32_t)k + (uint32_t)lane;   // < 1536
        const uint32_t r   = (x * 2731u) >> 16;                    // x / 24
        const uint32_t c4  = x - 24u * r;                          // x % 24
        const uint32_t gsw = c4 ^ (r & 7u);
        off32[k] = (((uint32_t)s0 + r) * (uint32_t)T_LEN + 4u * gsw) * 4u;
    }

    const char* sbase = (const char*)series;
    char*       lbase = (char*)lds_f;

    // prologue: tiles 0 and 1 in flight
    STAGE(0, 0);
    STAGE(1, 1);

    float  smooth = 0.0f;
    float4 tl[8];                 // tail (t=2016..2047), loaded at n==20
    int cur  = 0;                 // buffer holding tile n
    int nxt2 = 2;                 // buffer for tile n+2

#pragma unroll 1
    for (int n = 0; n < N_TILES; ++n) {
        if (n + 2 < N_TILES) {
            STAGE(n + 2, nxt2);
        }
        if (n == N_TILES - 1) {
            // hoist tail loads so they fly during the last tile's compute
            const float4* rowp = (const float4*)(series + (size_t)b * T_LEN);
#pragma unroll
            for (int j = 0; j < 8; ++j) tl[j] = rowp[504 + j];   // t=2016..2047
        }
        // counted waits: tile n's 24 loads retired when only the newer
        // prefetches remain outstanding (in-order vmcnt retirement).
        if (n + 2 < N_TILES)      { asm volatile("s_waitcnt vmcnt(48)" ::: "memory"); }
        else if (n + 1 < N_TILES) { asm volatile("s_waitcnt vmcnt(24)" ::: "memory"); }
        else                      { asm volatile("s_waitcnt vmcnt(8)"  ::: "memory"); }
        __builtin_amdgcn_sched_barrier(0);

        const int bufb = cur * TILE_BYTES;
        if (n == 0) {
            BODY24(bufb, 0, true);      // u=0 is smooth init
            BODY24(bufb, 1, false);
            BODY24(bufb, 2, false);
            BODY24(bufb, 3, false);
        } else {
            BODY24(bufb, 0, false);
            BODY24(bufb, 1, false);
            BODY24(bufb, 2, false);
            BODY24(bufb, 3, false);
        }
        cur  = (cur  == NBUF - 1) ? 0 : cur  + 1;
        nxt2 = (nxt2 == NBUF - 1) ? 0 : nxt2 + 1;
    }

    // tail: t = 2016..2047 (2016 % 24 == 0 -> idx = u % 24, static per u)
#pragma unroll
    for (int u = 0; u < 32; ++u) {
        const float4 q_ = tl[u >> 2];
        const int c_ = u & 3;
        const float v_ = (c_ == 0) ? q_.x : (c_ == 1) ? q_.y :
                         (c_ == 2) ? q_.z : q_.w;
        STEPX(v_, u % 24);
    }

    // predictions: out[b][j] = smooth + seas[(2048 + j) % 24]; 2048 % 24 == 8
    float4* __restrict__ o4 = reinterpret_cast<float4*>(out + (size_t)b * NPRED);
#pragma unroll
    for (int j4 = 0; j4 < NPRED / 4; ++j4) {
        float4 o;
        o.x = smooth + seas[(8 + j4 * 4 + 0) % 24];
        o.y = smooth + seas[(8 + j4 * 4 + 1) % 24];
        o.z = smooth + seas[(8 + j4 * 4 + 2) % 24];
        o.w = smooth + seas[(8 + j4 * 4 + 3) % 24];
        o4[j4] = o;
    }
}

extern "C" void kernel_launch(void* const* d_in, const int* in_sizes, int n_in,
                              void* d_out, int out_size, void* d_ws, size_t ws_size,
                              hipStream_t stream) {
    const float* series      = (const float*)d_in[0];
    const int*   shifts      = (const int*)  d_in[1];
    const float* alpha_p     = (const float*)d_in[2];
    const float* gamma_p     = (const float*)d_in[3];
    const float* init_season = (const float*)d_in[4];
    float*       out         = (float*)d_out;

    const int Bn = in_sizes[1];                  // 32768 series
    hw_kernel<<<Bn / 64, 64, 0, stream>>>(
        series, shifts, alpha_p, gamma_p, init_season, out);
}